// Round 9
// baseline (483.222 us; speedup 1.0000x reference)
//
#include <hip/hip_runtime.h>
#include <hip/hip_fp16.h>
#include <cstdint>

#define HIDDEN 128
#define MTOT 16

typedef float vfloat4 __attribute__((ext_vector_type(4)));
typedef float vfloat2 __attribute__((ext_vector_type(2)));

// ---------------------------------------------------------------------------
// Zero-fill (used for the fp16 accumulation buffer chi_h, 1.6 MB).
// ---------------------------------------------------------------------------
__global__ __launch_bounds__(256) void zero_kernel(float4* __restrict__ p,
                                                   int n4) {
  int i = blockIdx.x * 256 + threadIdx.x;
  int stride = gridDim.x * 256;
  float4 z = {0.f, 0.f, 0.f, 0.f};
  for (; i < n4; i += stride) p[i] = z;
}

// ---------------------------------------------------------------------------
// Convert fp16 accumulator -> f32 d_out (overwrites all of d_out; replaces
// the d_out zeroing pass).
// ---------------------------------------------------------------------------
__global__ __launch_bounds__(256) void convert_kernel(
    const __half* __restrict__ in, float* __restrict__ out, int n) {
  int i = (blockIdx.x * 256 + threadIdx.x) * 8;
  if (i < n) {
    uint4 raw = *(const uint4*)(in + i);  // 8 halves
    const __half2* h = (const __half2*)&raw;
    float2 f0 = __half22float2(h[0]);
    float2 f1 = __half22float2(h[1]);
    float2 f2 = __half22float2(h[2]);
    float2 f3 = __half22float2(h[3]);
    float4 o0 = {f0.x, f0.y, f1.x, f1.y};
    float4 o1 = {f2.x, f2.y, f3.x, f3.y};
    *(float4*)(out + i) = o0;
    *(float4*)(out + i + 4) = o1;
  }
}

// ---------------------------------------------------------------------------
// q/k projection, fp16 output. W in LDS, float4-preserving XOR swizzle.
// 8-row unroll: one ds_read_b128 feeds 32 FMAs.
// ---------------------------------------------------------------------------
__global__ __launch_bounds__(256) void proj_kernel(
    const float* __restrict__ x, const float* __restrict__ W,
    __half* __restrict__ out, int n_rows, float scale) {
  __shared__ float sW[128 * 128];  // 64 KB, swizzled
  for (int i = threadIdx.x; i < 128 * 128; i += 256) {
    int j = i >> 7, d = i & 127;
    sW[j * 128 + (d ^ ((j & 7) << 2))] = W[i] * scale;
  }
  __syncthreads();

  const int col = threadIdx.x & 127;
  const int g   = threadIdx.x >> 7;
  const int sx  = (col & 7) << 2;
  const float* sWc = sW + col * 128;

  const int row0 = blockIdx.x * 64;
#pragma unroll 1
  for (int m = 0; m < 4; ++m) {
    int r0 = row0 + g * 8 + m * 16;
    if (r0 >= n_rows) break;
    const float4* x4 = (const float4*)(x + (size_t)r0 * HIDDEN);
    if (r0 + 7 < n_rows) {
      float a0 = 0.f, a1 = 0.f, a2 = 0.f, a3 = 0.f;
      float a4 = 0.f, a5 = 0.f, a6 = 0.f, a7 = 0.f;
#pragma unroll
      for (int d4 = 0; d4 < 32; ++d4) {
        float4 w4 = *(const float4*)(sWc + ((d4 << 2) ^ sx));
        float4 xv0 = x4[d4];
        float4 xv1 = x4[32 + d4];
        float4 xv2 = x4[64 + d4];
        float4 xv3 = x4[96 + d4];
        float4 xv4 = x4[128 + d4];
        float4 xv5 = x4[160 + d4];
        float4 xv6 = x4[192 + d4];
        float4 xv7 = x4[224 + d4];
        a0 += xv0.x * w4.x + xv0.y * w4.y + xv0.z * w4.z + xv0.w * w4.w;
        a1 += xv1.x * w4.x + xv1.y * w4.y + xv1.z * w4.z + xv1.w * w4.w;
        a2 += xv2.x * w4.x + xv2.y * w4.y + xv2.z * w4.z + xv2.w * w4.w;
        a3 += xv3.x * w4.x + xv3.y * w4.y + xv3.z * w4.z + xv3.w * w4.w;
        a4 += xv4.x * w4.x + xv4.y * w4.y + xv4.z * w4.z + xv4.w * w4.w;
        a5 += xv5.x * w4.x + xv5.y * w4.y + xv5.z * w4.z + xv5.w * w4.w;
        a6 += xv6.x * w4.x + xv6.y * w4.y + xv6.z * w4.z + xv6.w * w4.w;
        a7 += xv7.x * w4.x + xv7.y * w4.y + xv7.z * w4.z + xv7.w * w4.w;
      }
      out[(size_t)(r0 + 0) * HIDDEN + col] = __float2half(a0);
      out[(size_t)(r0 + 1) * HIDDEN + col] = __float2half(a1);
      out[(size_t)(r0 + 2) * HIDDEN + col] = __float2half(a2);
      out[(size_t)(r0 + 3) * HIDDEN + col] = __float2half(a3);
      out[(size_t)(r0 + 4) * HIDDEN + col] = __float2half(a4);
      out[(size_t)(r0 + 5) * HIDDEN + col] = __float2half(a5);
      out[(size_t)(r0 + 6) * HIDDEN + col] = __float2half(a6);
      out[(size_t)(r0 + 7) * HIDDEN + col] = __float2half(a7);
    } else {
      for (int r = r0; r < n_rows; ++r) {
        const float4* xr = (const float4*)(x + (size_t)r * HIDDEN);
        float a = 0.f;
        for (int d4 = 0; d4 < 32; ++d4) {
          float4 w4 = *(const float4*)(sWc + ((d4 << 2) ^ sx));
          float4 xv = xr[d4];
          a += xv.x * w4.x + xv.y * w4.y + xv.z * w4.z + xv.w * w4.w;
        }
        out[(size_t)r * HIDDEN + col] = __float2half(a);
      }
    }
  }
}

// lane l in [0,8) owns m-pair (2l, 2l+1); head-of-m lane offsets
#define SRC0(lane, halfbase) \
  ((halfbase) + ((((lane) >= 1) + ((lane) >= 2) + ((lane) >= 5)) << 3))
#define SRC1(lane, halfbase) \
  ((halfbase) + ((1 + ((lane) >= 2) + ((lane) >= 4)) << 3))

__device__ __forceinline__ void pk_scatter(__half* __restrict__ chi,
                                           uint32_t dst, int lane,
                                           float am0, float am1, vfloat2 s2) {
  __half2 hv = __halves2half2(__float2half(am0 * s2.x),
                              __float2half(am1 * s2.y));
  uint32_t bits = *(uint32_t*)&hv;
  __half* p2 = chi + (size_t)dst * MTOT + (lane << 1);
  asm volatile("global_atomic_pk_add_f16 %0, %1, off"
               :: "v"(p2), "v"(bits) : "memory");
}

// ---------------------------------------------------------------------------
// Edge kernel (R8 structure; scatter switched to packed fp16 atomics:
// 8 global_atomic_pk_add_f16 per edge instead of 16 f32 atomics).
// ---------------------------------------------------------------------------
__global__ __launch_bounds__(256) void edge_kernel(
    const __half* __restrict__ q, const __half* __restrict__ k,
    const float* __restrict__ w_ij, const float* __restrict__ sph,
    const int* __restrict__ ei, const float* __restrict__ cutoff,
    __half* __restrict__ chi, int E, int ngroups, int nb8) {
  const int rank     = (blockIdx.x & 7) * nb8 + (blockIdx.x >> 3);
  const int gid      = rank * 8 + (threadIdx.x >> 5);
  const int lane     = threadIdx.x & 31;
  const int halfbase = threadIdx.x & 32;
  const int src0     = SRC0(lane, halfbase);
  const int src1     = SRC1(lane, halfbase);

  int e = gid;
  for (; e + ngroups < E; e += 2 * ngroups) {
    const int e2 = e + ngroups;
    int srcA = __builtin_nontemporal_load(ei + e);
    int dstA = __builtin_nontemporal_load(ei + E + e);
    int srcB = __builtin_nontemporal_load(ei + e2);
    int dstB = __builtin_nontemporal_load(ei + E + e2);
    float cutA = __builtin_nontemporal_load(cutoff + e);
    float cutB = __builtin_nontemporal_load(cutoff + e2);
    vfloat4 wA = __builtin_nontemporal_load(
        (const vfloat4*)(w_ij + (size_t)e * HIDDEN) + lane);
    vfloat4 wB = __builtin_nontemporal_load(
        (const vfloat4*)(w_ij + (size_t)e2 * HIDDEN) + lane);
    union { uint2 u; __half2 h2[2]; } qA, kA, qB, kB;
    qA.u = *((const uint2*)(q + (size_t)dstA * HIDDEN) + lane);
    kA.u = *((const uint2*)(k + (size_t)srcA * HIDDEN) + lane);
    qB.u = *((const uint2*)(q + (size_t)dstB * HIDDEN) + lane);
    kB.u = *((const uint2*)(k + (size_t)srcB * HIDDEN) + lane);

    float2 qa01 = __half22float2(qA.h2[0]);
    float2 qa23 = __half22float2(qA.h2[1]);
    float2 ka01 = __half22float2(kA.h2[0]);
    float2 ka23 = __half22float2(kA.h2[1]);
    float pA = qa01.x * wA.x * ka01.x + qa01.y * wA.y * ka01.y +
               qa23.x * wA.z * ka23.x + qa23.y * wA.w * ka23.y;
    float2 qb01 = __half22float2(qB.h2[0]);
    float2 qb23 = __half22float2(qB.h2[1]);
    float2 kb01 = __half22float2(kB.h2[0]);
    float2 kb23 = __half22float2(kB.h2[1]);
    float pB = qb01.x * wB.x * kb01.x + qb01.y * wB.y * kb01.y +
               qb23.x * wB.z * kb23.x + qb23.y * wB.w * kb23.y;

    pA += __shfl_xor(pA, 1);
    pB += __shfl_xor(pB, 1);
    pA += __shfl_xor(pA, 2);
    pB += __shfl_xor(pB, 2);
    pA += __shfl_xor(pA, 4);
    pB += __shfl_xor(pB, 4);
    float alphaA = pA * cutA;
    float alphaB = pB * cutB;
    float amA0 = __shfl(alphaA, src0);
    float amA1 = __shfl(alphaA, src1);
    float amB0 = __shfl(alphaB, src0);
    float amB1 = __shfl(alphaB, src1);
    if (lane < 8) {
      vfloat2 sA = __builtin_nontemporal_load(
          (const vfloat2*)(sph + (size_t)e * MTOT) + lane);
      vfloat2 sB = __builtin_nontemporal_load(
          (const vfloat2*)(sph + (size_t)e2 * MTOT) + lane);
      pk_scatter(chi, (uint32_t)dstA, lane, amA0, amA1, sA);
      pk_scatter(chi, (uint32_t)dstB, lane, amB0, amB1, sB);
    }
  }
  if (e < E) {  // tail
    int src = __builtin_nontemporal_load(ei + e);
    int dst = __builtin_nontemporal_load(ei + E + e);
    vfloat4 w4 = __builtin_nontemporal_load(
        (const vfloat4*)(w_ij + (size_t)e * HIDDEN) + lane);
    union { uint2 u; __half2 h2[2]; } qa, ka;
    qa.u = *((const uint2*)(q + (size_t)dst * HIDDEN) + lane);
    ka.u = *((const uint2*)(k + (size_t)src * HIDDEN) + lane);
    float2 q01 = __half22float2(qa.h2[0]);
    float2 q23 = __half22float2(qa.h2[1]);
    float2 k01 = __half22float2(ka.h2[0]);
    float2 k23 = __half22float2(ka.h2[1]);
    float p = q01.x * w4.x * k01.x + q01.y * w4.y * k01.y +
              q23.x * w4.z * k23.x + q23.y * w4.w * k23.y;
    p += __shfl_xor(p, 1);
    p += __shfl_xor(p, 2);
    p += __shfl_xor(p, 4);
    float alpha = p * __builtin_nontemporal_load(cutoff + e);
    float am0 = __shfl(alpha, src0);
    float am1 = __shfl(alpha, src1);
    if (lane < 8) {
      vfloat2 s2 = __builtin_nontemporal_load(
          (const vfloat2*)(sph + (size_t)e * MTOT) + lane);
      pk_scatter(chi, (uint32_t)dst, lane, am0, am1, s2);
    }
  }
}

extern "C" void kernel_launch(void* const* d_in, const int* in_sizes, int n_in,
                              void* d_out, int out_size, void* d_ws, size_t ws_size,
                              hipStream_t stream) {
  // inputs: chi, sph_ij, x, w_ij, edge_index, cutoff, Wq, Wk
  const float* sph    = (const float*)d_in[1];
  const float* x      = (const float*)d_in[2];
  const float* w_ij   = (const float*)d_in[3];
  const int*   ei     = (const int*)d_in[4];
  const float* cutoff = (const float*)d_in[5];
  const float* Wq     = (const float*)d_in[6];
  const float* Wk     = (const float*)d_in[7];
  float* out = (float*)d_out;

  const int n_nodes = in_sizes[0] / MTOT;  // chi is [N, 16]
  const int E       = in_sizes[5];         // cutoff is [E, 1]

  // ws: q fp16 (12.8MB) | k fp16 (12.8MB) | chi_h fp16 accumulator (1.6MB)
  __half* q = (__half*)d_ws;
  __half* k = q + (size_t)n_nodes * HIDDEN;
  __half* chi_h = k + (size_t)n_nodes * HIDDEN;

  // zero the fp16 accumulator (out_size halves = out_size*2 bytes)
  const int nz4 = out_size * 2 / 16;  // float4 count covering chi_h
  zero_kernel<<<128, 256, 0, stream>>>((float4*)chi_h, nz4);

  const int pgrid = (n_nodes + 63) / 64;
  const float inv_sqrt_hd = 0.17677669529663687f;  // 1/sqrt(32)
  proj_kernel<<<pgrid, 256, 0, stream>>>(x, Wq, q, n_nodes, inv_sqrt_hd);
  proj_kernel<<<pgrid, 256, 0, stream>>>(x, Wk, k, n_nodes, 1.0f);

  const int NB = 20000;  // multiple of 8; 160000 groups, 10 edges each
  const int ngroups = NB * 8;
  edge_kernel<<<NB, 256, 0, stream>>>(q, k, w_ij, sph, ei, cutoff, chi_h, E,
                                      ngroups, NB / 8);

  convert_kernel<<<(out_size / 8 + 255) / 256, 256, 0, stream>>>(chi_h, out,
                                                                 out_size);
}